// Round 1
// baseline (155.735 us; speedup 1.0000x reference)
//
#include <hip/hip_runtime.h>

#define NI 64
#define NJ 8192
#define NK 128
#define JT 2
#define XS_STRIDE 257   // JT*NK + 1 pad -> conflict-free row reads

// workspace float offsets
#define WS_M    0        // M[k'][k] = sum_c Wk[c][k'] * Wq[c][k]   (16384)
#define WS_WVT  16384    // WvT[k][c] = Wv[c][k]                    (16384)
#define WS_D    32768    // d[k] = sum_c Wq[c][k]*bk[c]             (128)
#define WS_W    32896    // w[k'] = sum_c bq[c]*Wk[c][k']           (128)
#define WS_S0   33024    // s0 = bk . bq                            (1)

__global__ __launch_bounds__(128) void precompute_kernel(
    const float* __restrict__ Wv,
    const float* __restrict__ Wq, const float* __restrict__ bq,
    const float* __restrict__ Wk, const float* __restrict__ bk,
    float* __restrict__ ws)
{
    const int b = blockIdx.x;    // k' in 0..127
    const int k = threadIdx.x;   // 0..127

    float macc = 0.f, dacc = 0.f;
    for (int c = 0; c < NK; ++c) {
        float wk = Wk[c*NK + b];        // uniform -> broadcast
        float wq = Wq[c*NK + k];        // coalesced
        macc += wk * wq;
        if (b == 0) dacc += bk[c] * wq;
    }
    ws[WS_M + b*NK + k] = macc;
    if (b == 0) ws[WS_D + k] = dacc;

    // transpose Wv for coalesced feat-phase reads
    ws[WS_WVT + b*NK + k] = Wv[k*NK + b];

    if (k == 0) {
        float wacc = 0.f;
        for (int c = 0; c < NK; ++c) wacc += bq[c] * Wk[c*NK + b];
        ws[WS_W + b] = wacc;
    }
    if (b == 0 && k == 1) {
        float s = 0.f;
        for (int c = 0; c < NK; ++c) s += bq[c] * bk[c];
        ws[WS_S0] = s;
    }
}

__global__ __launch_bounds__(256) void attcomms_main_kernel(
    const float* __restrict__ x, const float* __restrict__ bv,
    const int* __restrict__ pIdx, const float* __restrict__ ws,
    float* __restrict__ out)
{
    __shared__ float xs[NI][XS_STRIDE];   // 64 x 257 floats = 65792 B
    __shared__ float kq_s[JT][NK];
    __shared__ float att_s[JT][NI];
    __shared__ float y_s[JT][NK];
    __shared__ float beta_s[JT];

    const int tid  = threadIdx.x;
    const int lane = tid & 63;
    const int wave = tid >> 6;
    const int j0   = blockIdx.x * JT;

    const float* __restrict__ M   = ws + WS_M;
    const float* __restrict__ WvT = ws + WS_WVT;
    const float* __restrict__ dv  = ws + WS_D;
    const float* __restrict__ wv  = ws + WS_W;

    // ---- stage X tile: rows i = wave + 4t, 1 KB per row (2 j's x 128 k) ----
    const float* xbase = x + (size_t)j0 * NK + (size_t)(lane * 4);
    float4 buf[16];
#pragma unroll
    for (int t = 0; t < 16; ++t) {
        int i = wave + t * 4;
        buf[t] = *(const float4*)(xbase + (size_t)i * (size_t)(NJ * NK));
    }
#pragma unroll
    for (int t = 0; t < 16; ++t) {
        int i = wave + t * 4;
        float* dst = &xs[i][lane * 4];
        dst[0] = buf[t].x; dst[1] = buf[t].y; dst[2] = buf[t].z; dst[3] = buf[t].w;
    }
    __syncthreads();

    const int idx = *pIdx;

    // ---- kq[jj][k] = d[k] + sum_k' x3[jj][k'] * M[k'][k] ----
    {
        const int k  = tid & 127;
        const int jj = tid >> 7;
        const float* x3 = &xs[idx][jj * NK];   // uniform per wave -> broadcast
        float acc = dv[k];
#pragma unroll 8
        for (int kp = 0; kp < NK; ++kp)
            acc += x3[kp] * M[kp*NK + k];      // M coalesced across lanes
        kq_s[jj][k] = acc;
    }
    // ---- beta[jj] = s0 + sum_k' x3[jj][k'] * w[k'] (waves 0,1) ----
    if (tid < 128) {
        const int jj = wave;   // 0 or 1
        float p = xs[idx][jj*NK + lane]      * wv[lane]
                + xs[idx][jj*NK + lane + 64] * wv[lane + 64];
        for (int off = 32; off >= 1; off >>= 1) p += __shfl_xor(p, off);
        if (lane == 0) beta_s[jj] = p + ws[WS_S0];
    }
    __syncthreads();

    // ---- att[i,jj] = x[i,jj,:] . kq[jj] + beta[jj]; softmax over i ----
    if (tid < 128) {
        const int i  = lane;
        const int jj = wave;   // wave0 -> jj0, wave1 -> jj1
        const float* row = &xs[i][jj * NK];    // bank (i+k)%32 -> conflict-free
        float acc = beta_s[jj];
#pragma unroll 8
        for (int k = 0; k < NK; ++k)
            acc += row[k] * kq_s[jj][k];       // kq broadcast
        float m = acc;
        for (int off = 32; off >= 1; off >>= 1) m = fmaxf(m, __shfl_xor(m, off));
        float e = __expf(acc - m);
        float s = e;
        for (int off = 32; off >= 1; off >>= 1) s += __shfl_xor(s, off);
        att_s[jj][i] = e / s;
    }
    __syncthreads();

    // ---- y[jj][k] = sum_i att'[i,jj] * x[i,jj,k] ----
    {
        const int k  = tid & 127;
        const int jj = tid >> 7;
        float acc = 0.f;
#pragma unroll 8
        for (int i = 0; i < NI; ++i)
            acc += att_s[jj][i] * xs[i][jj*NK + k];   // conflict-free
        y_s[jj][k] = acc;
    }
    __syncthreads();

    // ---- feat[jj][c] = bv[c] + sum_k y[jj][k] * WvT[k][c] ----
    {
        const int c  = tid & 127;
        const int jj = tid >> 7;
        float acc = bv[c];
#pragma unroll 8
        for (int k = 0; k < NK; ++k)
            acc += y_s[jj][k] * WvT[k*NK + c];        // coalesced
        out[(size_t)(j0 + jj) * NK + c] = acc;
    }
}

extern "C" void kernel_launch(void* const* d_in, const int* in_sizes, int n_in,
                              void* d_out, int out_size, void* d_ws, size_t ws_size,
                              hipStream_t stream) {
    const float* x  = (const float*)d_in[0];
    const float* Wv = (const float*)d_in[1];
    const float* bv = (const float*)d_in[2];
    const float* Wq = (const float*)d_in[3];
    const float* bq = (const float*)d_in[4];
    const float* Wk = (const float*)d_in[5];
    const float* bk = (const float*)d_in[6];
    const int*  idx = (const int*)d_in[7];
    float* ws  = (float*)d_ws;
    float* out = (float*)d_out;

    precompute_kernel<<<NK, NK, 0, stream>>>(Wv, Wq, bq, Wk, bk, ws);
    attcomms_main_kernel<<<NJ / JT, 256, 0, stream>>>(x, bv, idx, ws, out);
}

// Round 2
// 109.045 us; speedup vs baseline: 1.4282x; 1.4282x over previous
//
#include <hip/hip_runtime.h>

#define NI 64
#define NJ 8192
#define NK 128
#define GMAIN 2048   // main-kernel grid; NJ/GMAIN = 4 tiles per block

// workspace float offsets
#define WS_M    0         // M[kp][k] = sum_c Wk[c][kp]*Wq[c][k]   (16384)
#define WS_WVT  16384     // WvT[kp][c] = Wv[c][kp]                (16384)
#define WS_D    32768     // d[k] = sum_c Wq[c][k]*bk[c]           (128)
#define WS_KQ   32896     // kq[j][k]                              (NJ*NK)

// ---------------- K1: tiny precompute of M, WvT, d ----------------
__global__ __launch_bounds__(128) void precompute_kernel(
    const float* __restrict__ Wv, const float* __restrict__ Wq,
    const float* __restrict__ Wk, const float* __restrict__ bk,
    float* __restrict__ ws)
{
    const int b = blockIdx.x;    // kp
    const int k = threadIdx.x;   // k
    float macc = 0.f, dacc = 0.f;
    for (int c = 0; c < NK; ++c) {
        float wq = Wq[c*NK + k];          // coalesced
        macc += Wk[c*NK + b] * wq;        // Wk col: uniform per block
        if (b == 0) dacc += bk[c] * wq;
    }
    ws[WS_M + b*NK + k] = macc;
    ws[WS_WVT + b*NK + k] = Wv[k*NK + b];
    if (b == 0) ws[WS_D + k] = dacc;
}

// ---------------- K2: kq[j,k] = d[k] + sum_kp x3[j,kp]*M[kp,k] ----------------
// block: 256 thr = 4 waves; wave owns 4 j's; lane = k-pair. No LDS.
__global__ __launch_bounds__(256) void kq_kernel(
    const float* __restrict__ x, const int* __restrict__ pIdx,
    const float* __restrict__ ws, float* __restrict__ kqout)
{
    const int tid = threadIdx.x;
    const int k2  = tid & 63;          // k-pair index: k in {2k2, 2k2+1}
    const int wv  = tid >> 6;
    const int j0  = blockIdx.x * 16 + wv * 4;
    const int idx = *pIdx;
    const float* __restrict__ M  = ws + WS_M;
    const float* __restrict__ x3 = x + (size_t)idx * NJ * NK;

    const float* r0 = x3 + (size_t)(j0+0)*NK;
    const float* r1 = x3 + (size_t)(j0+1)*NK;
    const float* r2 = x3 + (size_t)(j0+2)*NK;
    const float* r3 = x3 + (size_t)(j0+3)*NK;

    float d0 = ws[WS_D + 2*k2], d1 = ws[WS_D + 2*k2 + 1];
    float2 acc[4];
#pragma unroll
    for (int jj = 0; jj < 4; ++jj) { acc[jj].x = d0; acc[jj].y = d1; }

#pragma unroll 2
    for (int kp = 0; kp < NK; kp += 4) {
        float4 x0 = *(const float4*)(r0 + kp);   // uniform per wave -> 1 txn
        float4 x1 = *(const float4*)(r1 + kp);
        float4 x2 = *(const float4*)(r2 + kp);
        float4 x3v = *(const float4*)(r3 + kp);
        float2 m0 = *(const float2*)(M + (kp+0)*NK + 2*k2);  // coalesced
        float2 m1 = *(const float2*)(M + (kp+1)*NK + 2*k2);
        float2 m2 = *(const float2*)(M + (kp+2)*NK + 2*k2);
        float2 m3 = *(const float2*)(M + (kp+3)*NK + 2*k2);
        acc[0].x += x0.x*m0.x + x0.y*m1.x + x0.z*m2.x + x0.w*m3.x;
        acc[0].y += x0.x*m0.y + x0.y*m1.y + x0.z*m2.y + x0.w*m3.y;
        acc[1].x += x1.x*m0.x + x1.y*m1.x + x1.z*m2.x + x1.w*m3.x;
        acc[1].y += x1.x*m0.y + x1.y*m1.y + x1.z*m2.y + x1.w*m3.y;
        acc[2].x += x2.x*m0.x + x2.y*m1.x + x2.z*m2.x + x2.w*m3.x;
        acc[2].y += x2.x*m0.y + x2.y*m1.y + x2.z*m2.y + x2.w*m3.y;
        acc[3].x += x3v.x*m0.x + x3v.y*m1.x + x3v.z*m2.x + x3v.w*m3.x;
        acc[3].y += x3v.x*m0.y + x3v.y*m1.y + x3v.z*m2.y + x3v.w*m3.y;
    }
#pragma unroll
    for (int jj = 0; jj < 4; ++jj)
        *(float2*)(kqout + (size_t)(j0+jj)*NK + 2*k2) = acc[jj];
}

// ---------------- K3: att + softmax + y (streams all of x once) ----------------
__global__ __launch_bounds__(256, 4) void att_y_kernel(
    const float* __restrict__ x, const float* __restrict__ kq,
    float* __restrict__ y)
{
    __shared__ float att_s[NI];
    __shared__ float y_part[4*NK];

    const int tid  = threadIdx.x;
    const int lane = tid & 63;
    const int wave = tid >> 6;
    const int half = lane >> 5;
    const int lq   = lane & 31;
    const int k0   = lq * 4;
    const int ibase = wave*16 + half*8;               // rows ibase..ibase+7
    const size_t ISTEP = (size_t)NJ * NK;

    const float* xb = x + (size_t)ibase * ISTEP + k0;

    float4 A[8], B[8];

    auto issue = [&](int j, float4 (&buf)[8]) {
        const float* p = xb + (size_t)j * NK;
#pragma unroll
        for (int t = 0; t < 8; ++t)
            buf[t] = *(const float4*)(p + (size_t)t * ISTEP);
    };
    auto lkq = [&](int j) -> float4 {
        return *(const float4*)(kq + (size_t)j * NK + k0);
    };

    auto process = [&](int j, float4 (&buf)[8], float4 kqv) {
        float p[8];
#pragma unroll
        for (int t = 0; t < 8; ++t)
            p[t] = buf[t].x*kqv.x + buf[t].y*kqv.y + buf[t].z*kqv.z + buf[t].w*kqv.w;
        // reduce each p[t] over the 32-lane half
#pragma unroll
        for (int t = 0; t < 8; ++t) {
            p[t] += __shfl_xor(p[t], 1);
            p[t] += __shfl_xor(p[t], 2);
            p[t] += __shfl_xor(p[t], 4);
            p[t] += __shfl_xor(p[t], 8);
            p[t] += __shfl_xor(p[t], 16);
        }
#pragma unroll
        for (int t = 0; t < 8; ++t)
            if (lq == t) att_s[ibase + t] = p[t];
        __syncthreads();
        if (tid < NI) {   // wave 0: softmax over 64 agents
            float v = att_s[tid];
            float m = v;
            m = fmaxf(m, __shfl_xor(m, 1));  m = fmaxf(m, __shfl_xor(m, 2));
            m = fmaxf(m, __shfl_xor(m, 4));  m = fmaxf(m, __shfl_xor(m, 8));
            m = fmaxf(m, __shfl_xor(m, 16)); m = fmaxf(m, __shfl_xor(m, 32));
            float e = __expf(v - m);
            float s = e;
            s += __shfl_xor(s, 1);  s += __shfl_xor(s, 2);
            s += __shfl_xor(s, 4);  s += __shfl_xor(s, 8);
            s += __shfl_xor(s, 16); s += __shfl_xor(s, 32);
            att_s[tid] = e / s;
        }
        __syncthreads();
        float4 acc = make_float4(0.f, 0.f, 0.f, 0.f);
#pragma unroll
        for (int t = 0; t < 8; ++t) {
            float a = att_s[ibase + t];   // broadcast
            acc.x += a * buf[t].x; acc.y += a * buf[t].y;
            acc.z += a * buf[t].z; acc.w += a * buf[t].w;
        }
        acc.x += __shfl_xor(acc.x, 32); acc.y += __shfl_xor(acc.y, 32);
        acc.z += __shfl_xor(acc.z, 32); acc.w += __shfl_xor(acc.w, 32);
        if (half == 0)
            *(float4*)&y_part[wave*NK + k0] = acc;
        __syncthreads();
        if (tid < NK) {
            float s = y_part[tid] + y_part[NK+tid] + y_part[2*NK+tid] + y_part[3*NK+tid];
            y[(size_t)j * NK + tid] = s;
        }
    };

    const int j0 = blockIdx.x;
    issue(j0, A);             float4 kqA = lkq(j0);
    issue(j0 + GMAIN, B);     float4 kqB = lkq(j0 + GMAIN);
    process(j0, A, kqA);
    issue(j0 + 2*GMAIN, A);   kqA = lkq(j0 + 2*GMAIN);
    process(j0 + GMAIN, B, kqB);
    issue(j0 + 3*GMAIN, B);   kqB = lkq(j0 + 3*GMAIN);
    process(j0 + 2*GMAIN, A, kqA);
    process(j0 + 3*GMAIN, B, kqB);
}

// ---------------- K4: feat[j,c] = bv[c] + sum_kp y[j,kp]*WvT[kp,c] (in-place in d_out) ----------------
__global__ __launch_bounds__(256) void feat_kernel(
    float* __restrict__ yio, const float* __restrict__ bv,
    const float* __restrict__ ws)
{
    const int tid = threadIdx.x;
    const int k2  = tid & 63;
    const int wv  = tid >> 6;
    const int j0  = blockIdx.x * 16 + wv * 4;
    const float* __restrict__ W = ws + WS_WVT;

    const float* r0 = yio + (size_t)(j0+0)*NK;
    const float* r1 = yio + (size_t)(j0+1)*NK;
    const float* r2 = yio + (size_t)(j0+2)*NK;
    const float* r3 = yio + (size_t)(j0+3)*NK;

    float b0 = bv[2*k2], b1 = bv[2*k2 + 1];
    float2 acc[4];
#pragma unroll
    for (int jj = 0; jj < 4; ++jj) { acc[jj].x = b0; acc[jj].y = b1; }

#pragma unroll 2
    for (int kp = 0; kp < NK; kp += 4) {
        float4 x0 = *(const float4*)(r0 + kp);
        float4 x1 = *(const float4*)(r1 + kp);
        float4 x2 = *(const float4*)(r2 + kp);
        float4 x3v = *(const float4*)(r3 + kp);
        float2 m0 = *(const float2*)(W + (kp+0)*NK + 2*k2);
        float2 m1 = *(const float2*)(W + (kp+1)*NK + 2*k2);
        float2 m2 = *(const float2*)(W + (kp+2)*NK + 2*k2);
        float2 m3 = *(const float2*)(W + (kp+3)*NK + 2*k2);
        acc[0].x += x0.x*m0.x + x0.y*m1.x + x0.z*m2.x + x0.w*m3.x;
        acc[0].y += x0.x*m0.y + x0.y*m1.y + x0.z*m2.y + x0.w*m3.y;
        acc[1].x += x1.x*m0.x + x1.y*m1.x + x1.z*m2.x + x1.w*m3.x;
        acc[1].y += x1.x*m0.y + x1.y*m1.y + x1.z*m2.y + x1.w*m3.y;
        acc[2].x += x2.x*m0.x + x2.y*m1.x + x2.z*m2.x + x2.w*m3.x;
        acc[2].y += x2.x*m0.y + x2.y*m1.y + x2.z*m2.y + x2.w*m3.y;
        acc[3].x += x3v.x*m0.x + x3v.y*m1.x + x3v.z*m2.x + x3v.w*m3.x;
        acc[3].y += x3v.x*m0.y + x3v.y*m1.y + x3v.z*m2.y + x3v.w*m3.y;
    }
    // every load of rows j0..j0+3 feeds acc -> stores ordered after reads; rows
    // are owned by exactly this wave, so in-place overwrite is safe.
#pragma unroll
    for (int jj = 0; jj < 4; ++jj)
        *(float2*)(yio + (size_t)(j0+jj)*NK + 2*k2) = acc[jj];
}

extern "C" void kernel_launch(void* const* d_in, const int* in_sizes, int n_in,
                              void* d_out, int out_size, void* d_ws, size_t ws_size,
                              hipStream_t stream) {
    const float* x  = (const float*)d_in[0];
    const float* Wv = (const float*)d_in[1];
    const float* bv = (const float*)d_in[2];
    const float* Wq = (const float*)d_in[3];
    const float* bq = (const float*)d_in[4];  (void)bq;  // cancels in softmax
    const float* Wk = (const float*)d_in[5];
    const float* bk = (const float*)d_in[6];
    const int*  idx = (const int*)d_in[7];
    float* ws  = (float*)d_ws;
    float* out = (float*)d_out;

    precompute_kernel<<<NK, NK, 0, stream>>>(Wv, Wq, Wk, bk, ws);
    kq_kernel<<<NJ/16, 256, 0, stream>>>(x, idx, ws, ws + WS_KQ);
    att_y_kernel<<<GMAIN, 256, 0, stream>>>(x, ws + WS_KQ, out);   // out holds y
    feat_kernel<<<NJ/16, 256, 0, stream>>>(out, bv, ws);           // in-place y->feat
}